// Round 10
// baseline (300.851 us; speedup 1.0000x reference)
//
#include <hip/hip_runtime.h>
#include <math.h>

#define NB 8192
#define ND 128
#define NT 64          // 128-row tiles
#define NTRI 2080      // upper-triangle tile pairs
#define NPOSB 128      // per-label blocks (512 labels / 4 per block)
#define NBLK (NTRI + NPOSB)
#define NWORK 32       // row-finish worker blocks (last arrivals)
#define NLAB 512
#define MAXM 64

typedef unsigned short u16;
typedef unsigned int u32;
typedef __attribute__((ext_vector_type(8))) short bf16x8;
typedef __attribute__((ext_vector_type(4))) float f32x4;

#define G2 369.3299304675746f         // gamma * log2(e)
#define NEG_C (-23.083120654223414f)  // -G2/16
#define SENT (-1e30f)
#define LN2F 0.6931471805599453f

static __device__ __forceinline__ float fexp2(float x) {
  return __builtin_amdgcn_exp2f(x);
}

static __device__ __forceinline__ u32 f2bf(float f) {
  u32 u = __float_as_uint(f);
  return (u + 0x7FFF + ((u >> 16) & 1)) >> 16;   // RNE
}

static __device__ __forceinline__ float wave_sum_f(float v) {
  #pragma unroll
  for (int off = 1; off < 64; off <<= 1) v += __shfl_xor(v, off);
  return v;
}

// Load one row's MFMA fragment set from fp32, normalize in-register.
// Reduction tree: per-lane partial over cols {ks*32+lg*8..+8} (ks asc, elem
// asc), then xor-16, xor-32 across the 4 lg partners. ALL paths (triangle A,
// triangle B staging, pos) use this same tree -> bit-identical bf16.
static __device__ __forceinline__ void norm_frags(const float* __restrict__ src,
                                                  int lg, bf16x8 out[4]) {
  float v[4][8];
  #pragma unroll
  for (int ks = 0; ks < 4; ++ks) {
    const float4 a = *(const float4*)(src + ks * 32 + lg * 8);
    const float4 b = *(const float4*)(src + ks * 32 + lg * 8 + 4);
    v[ks][0] = a.x; v[ks][1] = a.y; v[ks][2] = a.z; v[ks][3] = a.w;
    v[ks][4] = b.x; v[ks][5] = b.y; v[ks][6] = b.z; v[ks][7] = b.w;
  }
  float ss = 0.f;
  #pragma unroll
  for (int ks = 0; ks < 4; ++ks)
    #pragma unroll
    for (int j = 0; j < 8; ++j) ss = fmaf(v[ks][j], v[ks][j], ss);
  ss += __shfl_xor(ss, 16);
  ss += __shfl_xor(ss, 32);
  const float inv = 1.0f / fmaxf(sqrtf(ss), 1e-12f);
  #pragma unroll
  for (int ks = 0; ks < 4; ++ks) {
    u32 wd[4];
    #pragma unroll
    for (int p = 0; p < 4; ++p)
      wd[p] = f2bf(v[ks][2 * p] * inv) | (f2bf(v[ks][2 * p + 1] * inv) << 16);
    bf16x8 f;
    #pragma unroll
    for (int p = 0; p < 4; ++p) ((u32*)&f)[p] = wd[p];
    out[ks] = f;
  }
}

__global__ __launch_bounds__(256, 3) void k_all(const float* __restrict__ emb,
                                                const int* __restrict__ labels,
                                                float* __restrict__ part,
                                                float* __restrict__ poscorr,
                                                float* __restrict__ bsum,
                                                int* __restrict__ counters,
                                                float* __restrict__ out) {
  __shared__ __align__(16) char S[33792];   // B tiles / labels+memL / colbuf
  __shared__ int sprev;
  __shared__ int lastf;
  __shared__ float svals[4], scnts[4];

  const int bid = blockIdx.x;
  const int tid = threadIdx.x;
  const int l = tid & 63;
  const int w = tid >> 6;
  const int lr_ = l & 15;
  const int lg = l >> 4;

  if (bid < NTRI) {
    // ============== upper-triangle sim tile (self-normalizing) =============
    int ti = (int)((129.0f - sqrtf(16641.0f - 8.0f * (float)bid)) * 0.5f);
    if (ti > NT - 1) ti = NT - 1;
    if (ti < 0) ti = 0;
    #define PRE(t) ((t) * NT - ((t) * ((t) - 1)) / 2)
    while (PRE(ti + 1) <= bid) ++ti;
    while (PRE(ti) > bid) --ti;
    const int tj = ti + (bid - PRE(ti));
    #undef PRE
    const int row0 = ti * 128;
    const int col0 = tj * 128;
    const bool diag = (ti == tj);

    // A fragments: normalize rows row0 + w*32 + m*16 + lr_ from fp32
    bf16x8 af[2][4];
    #pragma unroll
    for (int m = 0; m < 2; ++m)
      norm_frags(emb + (size_t)(row0 + w * 32 + m * 16 + lr_) * ND, lg, af[m]);

    // B staging: 256 threads; thread owns row srow = tid>>2, col-group q=tid&3
    // (cols {ks*32+q*8} -> same partial tree as norm_frags with q == lg).
    {
      const int srow = tid >> 2;
      const int q = tid & 3;
      #pragma unroll
      for (int h = 0; h < 2; ++h) {
        const float* src = emb + (size_t)(col0 + h * 64 + srow) * ND;
        float v[4][8];
        #pragma unroll
        for (int ks = 0; ks < 4; ++ks) {
          const float4 a = *(const float4*)(src + ks * 32 + q * 8);
          const float4 b = *(const float4*)(src + ks * 32 + q * 8 + 4);
          v[ks][0] = a.x; v[ks][1] = a.y; v[ks][2] = a.z; v[ks][3] = a.w;
          v[ks][4] = b.x; v[ks][5] = b.y; v[ks][6] = b.z; v[ks][7] = b.w;
        }
        float ss = 0.f;
        #pragma unroll
        for (int ks = 0; ks < 4; ++ks)
          #pragma unroll
          for (int j = 0; j < 8; ++j) ss = fmaf(v[ks][j], v[ks][j], ss);
        ss += __shfl_xor(ss, 1);
        ss += __shfl_xor(ss, 2);
        const float inv = 1.0f / fmaxf(sqrtf(ss), 1e-12f);
        #pragma unroll
        for (int ks = 0; ks < 4; ++ks) {
          u32 wd[4];
          #pragma unroll
          for (int p = 0; p < 4; ++p)
            wd[p] = f2bf(v[ks][2 * p] * inv) | (f2bf(v[ks][2 * p + 1] * inv) << 16);
          // swizzled LDS slot, same invariant as the old gload16 path:
          // LDS[row*256 + (s^(row&15))*16] holds global slot s = ks*4+q
          char* dst = S + h * 16384 + srow * 256 + (((ks * 4 + q) ^ (srow & 15)) * 16);
          #pragma unroll
          for (int p = 0; p < 4; ++p) ((u32*)dst)[p] = wd[p];
        }
      }
    }

    float sn[8], colp[8];
    #pragma unroll
    for (int q = 0; q < 8; ++q) { sn[q] = 0.f; colp[q] = 0.f; }

    __syncthreads();   // B tiles staged

    #pragma unroll
    for (int h = 0; h < 2; ++h) {
      const char* Bh = S + h * 16384;
      f32x4 acc[2][4];
      #pragma unroll
      for (int m = 0; m < 2; ++m)
        #pragma unroll
        for (int n = 0; n < 4; ++n)
          #pragma unroll
          for (int q = 0; q < 4; ++q) acc[m][n][q] = 0.f;

      #pragma unroll
      for (int ks = 0; ks < 4; ++ks) {
        const int kslot = (ks * 4 + lg) ^ lr_;   // read-side swizzle
        bf16x8 bfr[4];
        #pragma unroll
        for (int n = 0; n < 4; ++n)
          bfr[n] = *(const bf16x8*)(Bh + (n * 16 + lr_) * 256 + kslot * 16);
        #pragma unroll
        for (int m = 0; m < 2; ++m)
          #pragma unroll
          for (int n = 0; n < 4; ++n)
            acc[m][n] = __builtin_amdgcn_mfma_f32_16x16x32_bf16(af[m][ks], bfr[n],
                                                                acc[m][n], 0, 0, 0);
      }

      // epilogue: ev feeds row sums and (by symmetry) column sums
      #pragma unroll
      for (int m = 0; m < 2; ++m) {
        #pragma unroll
        for (int n = 0; n < 4; ++n) {
          const bool dmn = diag && (w * 32 + m * 16 == h * 64 + n * 16);
          float scc = 0.f;
          #pragma unroll
          for (int j = 0; j < 4; ++j) {
            const float sv = acc[m][n][j];
            float xn = fmaf(sv * sv, G2, NEG_C);
            xn = (sv > -0.25f) ? xn : 0.f;
            if (dmn) xn = (lr_ == lg * 4 + j) ? SENT : xn;  // drop true diagonal
            const float ev = fexp2(xn);
            sn[m * 4 + j] += ev;
            scc += ev;
          }
          colp[h * 4 + n] += scc;
        }
      }
    }

    // row sums: reduce over 16 column-lanes, write slot tj
    #pragma unroll
    for (int q = 0; q < 8; ++q) {
      #pragma unroll
      for (int off = 1; off < 16; off <<= 1) sn[q] += __shfl_xor(sn[q], off);
    }
    if (lr_ == 0) {
      #pragma unroll
      for (int m = 0; m < 2; ++m)
        #pragma unroll
        for (int j = 0; j < 4; ++j) {
          const int row = row0 + w * 32 + m * 16 + lg * 4 + j;
          part[(size_t)row * NT + tj] = sn[m * 4 + j];
        }
    }

    // column sums (non-diag): reduce lg groups, cross-wave via LDS
    if (!diag) {
      #pragma unroll
      for (int q = 0; q < 8; ++q) {
        colp[q] += __shfl_xor(colp[q], 16);
        colp[q] += __shfl_xor(colp[q], 32);
      }
      __syncthreads();                   // all MFMA LDS reads done
      float* colbuf = (float*)S;
      if (l < 16) {
        #pragma unroll
        for (int q = 0; q < 8; ++q)
          colbuf[w * 128 + (q >> 2) * 64 + (q & 3) * 16 + lr_] = colp[q];
      }
      __syncthreads();
      if (tid < 128) {
        const float cs_ = colbuf[tid] + colbuf[128 + tid] +
                          colbuf[256 + tid] + colbuf[384 + tid];
        part[(size_t)(col0 + tid) * NT + ti] = cs_;
      }
    }
  } else {
    // ============== per-label positives + same-label correction ============
    int* lab = (int*)S;                        // 8192 ints = 32 KB
    for (int i = tid; i < NB / 4; i += 256)
      ((int4*)lab)[i] = ((const int4*)labels)[i];
    __syncthreads();

    const int L = (bid - NTRI) * 4 + w;        // one wave per label
    int* memL = (int*)(S + 32768) + w * MAXM;

    int cnt = 0;
    for (int base = 0; base < NB; base += 64) {
      const int lv = lab[base + l];
      const unsigned long long mk = __ballot(lv == L);
      if (lv == L) {
        const int pos = __popcll(mk & ((1ull << l) - 1));
        if (cnt + pos < MAXM) memL[cnt + pos] = base + l;
      }
      cnt += __popcll(mk);
    }
    int c = cnt > MAXM ? MAXM : cnt;
    __syncthreads();

    const int nt = (c + 15) >> 4;
    for (int rb = 0; rb < nt; ++rb) {
      const int ri = rb * 16 + lr_;
      bf16x8 af[4];
      if (ri < c) {                            // uniform across lg partners
        norm_frags(emb + (size_t)memL[ri] * ND, lg, af);
      } else {
        #pragma unroll
        for (int ks = 0; ks < 4; ++ks) af[ks] = (bf16x8)0;
      }
      float corr[4], mp[4], sp[4];
      #pragma unroll
      for (int r = 0; r < 4; ++r) { corr[r] = 0.f; mp[r] = SENT; sp[r] = 0.f; }

      for (int cb = 0; cb < nt; ++cb) {
        const int ci = cb * 16 + lr_;
        bf16x8 bfr[4];
        if (ci < c) {
          norm_frags(emb + (size_t)memL[ci] * ND, lg, bfr);
        } else {
          #pragma unroll
          for (int ks = 0; ks < 4; ++ks) bfr[ks] = (bf16x8)0;
        }
        f32x4 acc;
        #pragma unroll
        for (int r = 0; r < 4; ++r) acc[r] = 0.f;
        #pragma unroll
        for (int ks = 0; ks < 4; ++ks)
          acc = __builtin_amdgcn_mfma_f32_16x16x32_bf16(af[ks], bfr[ks], acc, 0, 0, 0);

        #pragma unroll
        for (int r = 0; r < 4; ++r) {
          const int R = rb * 16 + lg * 4 + r;
          const int Cj = cb * 16 + lr_;
          const bool ok = (R < c) && (Cj < c) && (R != Cj);
          const float sv = acc[r];
          float xn = fmaf(sv * sv, G2, NEG_C);
          xn = (sv > -0.25f) ? xn : 0.f;
          corr[r] += ok ? fexp2(xn) : 0.f;
          if (ok) {
            const float t1 = 1.25f - sv;
            const float xp = G2 * fmaxf(t1, 0.f) * (t1 - 0.5f);
            if (xp > mp[r]) { sp[r] = sp[r] * fexp2(mp[r] - xp) + 1.f; mp[r] = xp; }
            else sp[r] += fexp2(xp - mp[r]);
          }
        }
      }
      #pragma unroll
      for (int r = 0; r < 4; ++r) {
        #pragma unroll
        for (int off = 1; off < 16; off <<= 1) {
          corr[r] += __shfl_xor(corr[r], off);
          const float m2 = __shfl_xor(mp[r], off), s2 = __shfl_xor(sp[r], off);
          const float M = fmaxf(mp[r], m2);
          const float t1 = sp[r] * fexp2(mp[r] - M);  // exp2(-1e30)=0 for empties
          const float t2 = s2 * fexp2(m2 - M);
          mp[r] = M; sp[r] = t1 + t2;
        }
      }
      if (lr_ == 0) {
        #pragma unroll
        for (int r = 0; r < 4; ++r) {
          const int R = rb * 16 + lg * 4 + r;
          if (R < c) {
            float* o = poscorr + (size_t)memL[R] * 4;
            o[0] = mp[r]; o[1] = sp[r]; o[2] = corr[r]; o[3] = (float)(c - 1);
          }
        }
      }
    }
  }

  // ================= arrival: last NWORK blocks finish the rows ============
  __syncthreads();
  __threadfence();                              // release part/poscorr writes
  if (tid == 0) sprev = atomicAdd(&counters[0], 1);
  __syncthreads();
  const int myPos = sprev;
  if (myPos < NBLK - NWORK) return;

  const int chunk = myPos - (NBLK - NWORK);
  if (tid == 0) {
    while (__hip_atomic_load(&counters[0], __ATOMIC_ACQUIRE,
                             __HIP_MEMORY_SCOPE_AGENT) < NBLK)
      __builtin_amdgcn_s_sleep(8);
  }
  __syncthreads();
  __threadfence();

  {
    const int row = chunk * 256 + tid;
    float sn = 0.f;
    const float* pp = part + (size_t)row * NT;
    #pragma unroll 8
    for (int q = 0; q < NT; ++q)
      sn += __hip_atomic_load(pp + q, __ATOMIC_RELAXED, __HIP_MEMORY_SCOPE_AGENT);
    const float* pcp = poscorr + (size_t)row * 4;
    float pc[4];
    #pragma unroll
    for (int q = 0; q < 4; ++q)
      pc[q] = __hip_atomic_load(pcp + q, __ATOMIC_RELAXED, __HIP_MEMORY_SCOPE_AGENT);
    const int npi = (int)(pc[3] + 0.5f);
    const bool valid = (npi > 0) && (npi < NB - 1);
    float val = 0.f;
    if (valid) {
      const float snn = fmaxf(sn - pc[2], 1e-30f);
      const float lp = LN2F * (pc[0] + log2f(pc[1]));
      const float ln_ = LN2F * log2f(snn);
      const float x = lp + ln_;
      val = fmaxf(x, 0.f) + log1pf(expf(-fabsf(x)));  // stable softplus
    }
    float cntv = valid ? 1.f : 0.f;
    val = wave_sum_f(val);
    cntv = wave_sum_f(cntv);
    if (l == 0) { svals[w] = val; scnts[w] = cntv; }
    __syncthreads();
    if (tid == 0) {
      bsum[chunk * 2 + 0] = svals[0] + svals[1] + svals[2] + svals[3];
      bsum[chunk * 2 + 1] = scnts[0] + scnts[1] + scnts[2] + scnts[3];
      __threadfence();
      lastf = (atomicAdd(&counters[1], 1) == NWORK - 1);
    }
    __syncthreads();
    if (lastf && w == 0) {
      __threadfence();
      float s = 0.f, c = 0.f;
      if (l < NWORK) {
        s = __hip_atomic_load(bsum + l * 2, __ATOMIC_RELAXED, __HIP_MEMORY_SCOPE_AGENT);
        c = __hip_atomic_load(bsum + l * 2 + 1, __ATOMIC_RELAXED, __HIP_MEMORY_SCOPE_AGENT);
      }
      s = wave_sum_f(s);
      c = wave_sum_f(c);
      if (l == 0) out[0] = s / fmaxf(c, 1.f);
    }
  }
}

extern "C" void kernel_launch(void* const* d_in, const int* in_sizes, int n_in,
                              void* d_out, int out_size, void* d_ws, size_t ws_size,
                              hipStream_t stream) {
  const float* emb = (const float*)d_in[0];
  const int* labels = (const int*)d_in[1];
  float* out = (float*)d_out;
  char* ws = (char*)d_ws;

  float* part    = (float*)(ws + 0);         // 8192*64*4 = 2097152
  float* poscorr = (float*)(ws + 2097152);   // 8192*4*4  = 131072
  float* bsum    = (float*)(ws + 2228224);   // 256 B
  int*   counters= (int*)  (ws + 2228480);   // 8 B

  hipMemsetAsync(counters, 0, 8, stream);
  k_all<<<NBLK, 256, 0, stream>>>(emb, labels, part, poscorr, bsum, counters, out);
}